// Round 17
// baseline (324.766 us; speedup 1.0000x reference)
//
#include <hip/hip_runtime.h>
#include <hip/hip_fp16.h>
#include <math.h>

// GCNII forward, fp16-compressed intermediates.
//   h0 = relu(x @ Wlin + b)                       [lin0: tiled GEMM, M=128]
//   per layer l: h = relu((0.9*(A@h) + 0.1*x0) @ W'_l)   [ONE fused kernel]
//   W'_l = (1-beta_l) I + beta_l W_l (premixed).
// Round-17: round-14 fused structure, but the dense phase broadcasts z
// IN-REGISTER via __shfl within each 8-lane group instead of staging z in
// LDS: removes the zs array (LDS 30.7->21.7KB) and the block-wide barrier
// between gather and dense (waves fully independent after the Ws load).
// Round-16's nontemporal streams reverted (hurt: 57.8->62us).
// lin0: reg-prefetch dbuf, writes only x0. CSR build: bucketed counting
// sort (no random sub-line global stores).
// Constants: N=100000, E=1600000, H=128, D=64, L=4.

#define DD 64
#define HH 128
#define M_TILE 128
#define K_CHUNK 32
#define NPB 128            // nodes per bucket (bucket = node>>7)
#define SLOT 2560          // record slots per bucket (mean ~2046, +11 sigma)
#define NBUK_MAX 1024
#define PART_BLOCKS 256
#define PART_THREADS 1024
#define GSTRIDE 17         // padded record-slot stride (int2) -> distinct banks
#define WPAD 68            // padded row stride (floats) for Ws

__device__ inline ushort f2h(float f) { return __half_as_ushort(__float2half(f)); }
__device__ inline float us2f(ushort u) { return __half2float(__ushort_as_half(u)); }

__global__ __launch_bounds__(256) void init_bcur(int* bcur, int nbuk) {
    int i = blockIdx.x * blockDim.x + threadIdx.x;
    if (i < nbuk) bcur[i] = i * SLOT;
}

// One-pass partition into bucket slots. Record: {row:17 | col_lo15:15},
// {col_hi2:2 | w_fp16:16<<2}.
__global__ __launch_bounds__(PART_THREADS) void partition_kernel(
    const int* __restrict__ row, const int* __restrict__ col,
    const float* __restrict__ ew, int* __restrict__ bcur,
    uint2* __restrict__ pk, int E, int nbuk) {
    __shared__ int cnt[NBUK_MAX], base[NBUK_MAX], rc[NBUK_MAX];
    int t = threadIdx.x;
    for (int i = t; i < nbuk; i += PART_THREADS) { cnt[i] = 0; rc[i] = 0; }
    __syncthreads();
    int chunk = (E + gridDim.x - 1) / gridDim.x;
    int s0 = blockIdx.x * chunk;
    int s1 = min(s0 + chunk, E);
    for (int e = s0 + t; e < s1; e += PART_THREADS)
        atomicAdd(&cnt[__builtin_nontemporal_load(&row[e]) >> 7], 1);
    __syncthreads();
    for (int i = t; i < nbuk; i += PART_THREADS)
        if (cnt[i] > 0) base[i] = atomicAdd(&bcur[i], cnt[i]);
    __syncthreads();
    for (int e = s0 + t; e < s1; e += PART_THREADS) {
        int r = __builtin_nontemporal_load(&row[e]);
        int c = __builtin_nontemporal_load(&col[e]);
        ushort wh = f2h(__builtin_nontemporal_load(&ew[e]));
        int b = r >> 7;
        int pos = base[b] + atomicAdd(&rc[b], 1);
        if (pos < (b + 1) * SLOT)   // defensive (SLOT is +11 sigma)
            pk[pos] = make_uint2((uint)r | (((uint)c & 0x7fffu) << 17),
                                 ((uint)c >> 15) | ((uint)wh << 2));
    }
}

// Per-bucket counting sort -> CSR segment at cw[b*SLOT ..] + rowptr2 pairs.
__global__ __launch_bounds__(256) void sort_kernel(
    const uint2* __restrict__ pk, const int* __restrict__ bcur,
    int2* __restrict__ cw, int2* __restrict__ rowptr2, int n) {
    __shared__ int hist[NPB], scan[NPB], rc[NPB];
    int b = blockIdx.x, lo = b << 7;
    int cnt = min(bcur[b] - b * SLOT, SLOT);
    const uint2* rec = pk + (size_t)b * SLOT;
    int t = threadIdx.x;
    if (t < NPB) { hist[t] = 0; rc[t] = 0; }
    __syncthreads();
    for (int i = t; i < cnt; i += 256)
        atomicAdd(&hist[(rec[i].x & 0x1ffffu) - lo], 1);
    __syncthreads();
    if (t < NPB) scan[t] = hist[t];
    __syncthreads();
    for (int off = 1; off < NPB; off <<= 1) {       // inclusive scan
        int v = (t < NPB && t >= off) ? scan[t - off] : 0;
        __syncthreads();
        if (t < NPB) scan[t] += v;
        __syncthreads();
    }
    if (t < NPB && lo + t < n) {
        int beg = b * SLOT + scan[t] - hist[t];     // exclusive base
        rowptr2[lo + t] = make_int2(beg, beg + hist[t]);
    }
    for (int i = t; i < cnt; i += 256) {
        uint2 r2 = rec[i];
        int nl = (int)(r2.x & 0x1ffffu) - lo;
        int c = (int)((r2.x >> 17) | ((r2.y & 3u) << 15));
        float w = us2f((ushort)((r2.y >> 2) & 0xffffu));
        int pos = (scan[nl] - hist[nl]) + atomicAdd(&rc[nl], 1);
        cw[b * SLOT + pos] = make_int2(c, __float_as_int(w));
    }
}

// W'_l = (1-beta_l) I + beta_l W_l, all L layers at once.
__global__ __launch_bounds__(256) void prep_w(const float* __restrict__ conv_w,
                                              float* __restrict__ Wp, int total) {
    int i = blockIdx.x * blockDim.x + threadIdx.x;
    if (i >= total) return;
    int l = i >> 12;
    int r = i & 4095;
    int d = r >> 6, j = r & 63;
    float beta = logf(0.5f / (float)(l + 1) + 1.0f);
    float v = beta * conv_w[i];
    if (d == j) v += 1.0f - beta;
    Wp[i] = v;
}

// h0 = relu(x @ Wlin + b) -> x0 only (layer-0 reads x0 directly).
// Register-tiled GEMM, thread = 8 nodes x 4 outs, 128-node tile.
// W from global (L1-hot); x tile in 16KB XOR-swizzled LDS; next x tile
// register-prefetched so HBM latency overlaps the 32-k compute.
__global__ __launch_bounds__(256) void lin0_kernel(
    const float* __restrict__ x, const float* __restrict__ Wlin,
    const float* __restrict__ b, ushort* __restrict__ x0, int n) {
    __shared__ float xs[K_CHUNK][M_TILE];      // 16 KB, swizzled columns
    int t = threadIdx.x;
    int tm = t >> 4, tn = t & 15;
    int m0 = blockIdx.x * M_TILE;

    float4 bb = *(const float4*)&b[tn * 4];
    float acc[8][4];
#pragma unroll
    for (int mi = 0; mi < 8; ++mi) {
        acc[mi][0] = bb.x; acc[mi][1] = bb.y; acc[mi][2] = bb.z; acc[mi][3] = bb.w;
    }

    // prefetch kk = 0
    float4 v[4];
#pragma unroll
    for (int i = 0; i < 4; ++i) {
        int s = t + i * 256;
        int node = s >> 3, cpos = (s & 7) * 4;
        int g = m0 + node;
        v[i] = (g < n) ? *(const float4*)&x[(size_t)g * HH + cpos]
                       : make_float4(0.f, 0.f, 0.f, 0.f);
    }

    for (int kk = 0; kk < HH; kk += K_CHUNK) {
        __syncthreads();                       // prev compute done
#pragma unroll
        for (int i = 0; i < 4; ++i) {
            int s = t + i * 256;
            int node = s >> 3, cpos = (s & 7) * 4;
            int q = (s & 7) & 3;
            int pc = node ^ (q << 3);          // swizzled column
            xs[cpos + 0][pc] = v[i].x;
            xs[cpos + 1][pc] = v[i].y;
            xs[cpos + 2][pc] = v[i].z;
            xs[cpos + 3][pc] = v[i].w;
        }
        __syncthreads();
        if (kk + K_CHUNK < HH) {               // prefetch next tile
#pragma unroll
            for (int i = 0; i < 4; ++i) {
                int s = t + i * 256;
                int node = s >> 3, cpos = (s & 7) * 4;
                int g = m0 + node;
                v[i] = (g < n)
                    ? *(const float4*)&x[(size_t)g * HH + kk + K_CHUNK + cpos]
                    : make_float4(0.f, 0.f, 0.f, 0.f);
            }
        }
#pragma unroll
        for (int k = 0; k < K_CHUNK; ++k) {
            float4 wv = *(const float4*)&Wlin[(size_t)(kk + k) * DD + tn * 4];
            int base = (tm * 8) ^ ((((k) >> 2) & 3) << 3);
            float4 xa = *(const float4*)&xs[k][base];
            float4 xb = *(const float4*)&xs[k][base + 4];
            float xm[8] = {xa.x, xa.y, xa.z, xa.w, xb.x, xb.y, xb.z, xb.w};
            float wj[4] = {wv.x, wv.y, wv.z, wv.w};
#pragma unroll
            for (int mi = 0; mi < 8; ++mi)
#pragma unroll
                for (int j = 0; j < 4; ++j)
                    acc[mi][j] += xm[mi] * wj[j];
        }
    }
#pragma unroll
    for (int mi = 0; mi < 8; ++mi) {
        int node = m0 + tm * 8 + mi;
        if (node >= n) continue;
        ushort4 o;
        o.x = f2h(fmaxf(acc[mi][0], 0.f));
        o.y = f2h(fmaxf(acc[mi][1], 0.f));
        o.z = f2h(fmaxf(acc[mi][2], 0.f));
        o.w = f2h(fmaxf(acc[mi][3], 0.f));
        *(ushort4*)&x0[(size_t)node * DD + tn * 4] = o;
    }
}

// Fused GCNII layer: z = 0.9*(A@h) + 0.1*x0 (gather, registers) ->
// dense h = relu(z @ W') with z broadcast via __shfl inside the 8-lane
// group (no zs LDS, no gather->dense barrier). Block = 32 nodes, 4 waves.
__global__ __launch_bounds__(256) void layer_kernel(
    const ushort* __restrict__ h_in, const ushort* __restrict__ x0,
    const int2* __restrict__ rowptr2, const int2* __restrict__ cw,
    const float* __restrict__ Wp, ushort* __restrict__ h_half,
    float* __restrict__ h_f32, int n) {
    __shared__ float Ws[DD][WPAD];        // 17.4 KB premixed W'
    __shared__ int2 es[4][8 * GSTRIDE];   // 4.3 KB edge records
    int t = threadIdx.x;

    // cooperative W' load: 4096 floats, 16 per thread (reused -> cached)
    {
        int k = t >> 2, j0 = (t & 3) * 16;
#pragma unroll
        for (int p = 0; p < 4; ++p)
            *(float4*)&Ws[k][j0 + p * 4] =
                *(const float4*)&Wp[(size_t)k * DD + j0 + p * 4];
    }
    __syncthreads();   // Ws ready; only barrier in the kernel

    // ---- phase 1: gather (8-lane group per node, 8 nodes/wave) ----
    int wave = t >> 6, lane = t & 63;
    int grp = lane >> 3, sub = lane & 7;
    int2* slot = &es[wave][grp * GSTRIDE];
    int node = blockIdx.x * 32 + wave * 8 + grp;
    bool nvalid = node < n;
    int nn = nvalid ? node : (n - 1);
    int2 rp = rowptr2[nn];
    int beg = rp.x;
    int end = nvalid ? rp.y : beg;
    uint4 x0v = *(const uint4*)&x0[(size_t)nn * DD + sub * 8];

    float acc[4][8];
#pragma unroll
    for (int c = 0; c < 4; ++c)
#pragma unroll
        for (int f = 0; f < 8; ++f) acc[c][f] = 0.f;

    for (int base = beg; base < end; base += 16) {
        int m = end - base;
        if (m > 16) m = 16;
        if (sub < m) slot[sub] = cw[base + sub];
        if (sub + 8 < m) slot[sub + 8] = cw[base + sub + 8];
        // same-wave LDS write->read; compiler orders via lgkmcnt
#pragma unroll
        for (int j = 0; j < 4; ++j) {
#pragma unroll
            for (int c = 0; c < 4; ++c) {
                int idx = j * 4 + c;
                bool vld = idx < m;
                int2 r = slot[vld ? idx : 0];
                float w = vld ? __int_as_float(r.y) : 0.f;
                uint4 hv = *(const uint4*)&h_in[(size_t)r.x * DD + sub * 8];
                acc[c][0] += w * us2f((ushort)(hv.x & 0xffff));
                acc[c][1] += w * us2f((ushort)(hv.x >> 16));
                acc[c][2] += w * us2f((ushort)(hv.y & 0xffff));
                acc[c][3] += w * us2f((ushort)(hv.y >> 16));
                acc[c][4] += w * us2f((ushort)(hv.z & 0xffff));
                acc[c][5] += w * us2f((ushort)(hv.z >> 16));
                acc[c][6] += w * us2f((ushort)(hv.w & 0xffff));
                acc[c][7] += w * us2f((ushort)(hv.w >> 16));
            }
        }
    }

    // z in registers: zreg[j] = feature sub*8+j of this group's node
    float zreg[8];
    {
        uint xp[4] = {x0v.x, x0v.y, x0v.z, x0v.w};
#pragma unroll
        for (int k = 0; k < 8; ++k) {
            float f = (acc[0][k] + acc[1][k]) + (acc[2][k] + acc[3][k]);
            float xv = (k & 1) ? us2f((ushort)(xp[k >> 1] >> 16))
                               : us2f((ushort)(xp[k >> 1] & 0xffff));
            zreg[k] = 0.9f * f + 0.1f * xv;
        }
    }

    // ---- phase 2: dense h = relu(z @ W'), z via in-group shfl ----
    int gb8 = lane & 56;                       // group base lane
    float o[8];
#pragma unroll
    for (int j = 0; j < 8; ++j) o[j] = 0.f;
#pragma unroll
    for (int k = 0; k < DD; ++k) {
        float zk = __shfl(zreg[k & 7], gb8 + (k >> 3), 64);
        float4 wa = *(const float4*)&Ws[k][sub * 8];
        float4 wb = *(const float4*)&Ws[k][sub * 8 + 4];
        o[0] += zk * wa.x; o[1] += zk * wa.y;
        o[2] += zk * wa.z; o[3] += zk * wa.w;
        o[4] += zk * wb.x; o[5] += zk * wb.y;
        o[6] += zk * wb.z; o[7] += zk * wb.w;
    }
    if (nvalid) {
#pragma unroll
        for (int j = 0; j < 8; ++j) o[j] = fmaxf(o[j], 0.f);
        if (h_f32) {
            *(float4*)&h_f32[(size_t)node * DD + sub * 8] =
                make_float4(o[0], o[1], o[2], o[3]);
            *(float4*)&h_f32[(size_t)node * DD + sub * 8 + 4] =
                make_float4(o[4], o[5], o[6], o[7]);
        } else {
            uint4 ov;
            ov.x = (uint)f2h(o[0]) | ((uint)f2h(o[1]) << 16);
            ov.y = (uint)f2h(o[2]) | ((uint)f2h(o[3]) << 16);
            ov.z = (uint)f2h(o[4]) | ((uint)f2h(o[5]) << 16);
            ov.w = (uint)f2h(o[6]) | ((uint)f2h(o[7]) << 16);
            *(uint4*)&h_half[(size_t)node * DD + sub * 8] = ov;
        }
    }
}

static inline size_t align256(size_t x) { return (x + 255) & ~(size_t)255; }

extern "C" void kernel_launch(void* const* d_in, const int* in_sizes, int n_in,
                              void* d_out, int out_size, void* d_ws, size_t ws_size,
                              hipStream_t stream) {
    const float* x      = (const float*)d_in[0];
    const int*   row    = (const int*)d_in[1];
    const int*   col    = (const int*)d_in[2];
    const float* ew     = (const float*)d_in[3];
    const float* w_lin  = (const float*)d_in[4];
    const float* b_lin  = (const float*)d_in[5];
    const float* conv_w = (const float*)d_in[6];
    float* out = (float*)d_out;

    const int N = in_sizes[0] / HH;          // 100000
    const int E = in_sizes[1];               // 1600000
    const int L = in_sizes[6] / (DD * DD);   // 4
    const int nbuk = (N + NPB - 1) / NPB;    // 782

    char* ws = (char*)d_ws;
    size_t off = 0;
    int* bcur = (int*)(ws + off);        off = align256(off + (size_t)NBUK_MAX * 4);
    uint2* pk = (uint2*)(ws + off);      off = align256(off + (size_t)nbuk * SLOT * 8);
    int2* cw = (int2*)(ws + off);        off = align256(off + (size_t)nbuk * SLOT * 8);
    int2* rowptr2 = (int2*)(ws + off);   off = align256(off + (size_t)N * 8);
    ushort* x0 = (ushort*)(ws + off);    off = align256(off + (size_t)N * DD * 2);
    ushort* hA = (ushort*)(ws + off);    off = align256(off + (size_t)N * DD * 2);
    ushort* hB = (ushort*)(ws + off);    off = align256(off + (size_t)N * DD * 2);
    float* Wp = (float*)(ws + off);      off = align256(off + (size_t)L * DD * DD * 4);
    (void)ws_size;

    const int mt = (N + M_TILE - 1) / M_TILE;   // 782
    const int gb = (N + 31) / 32;               // 3125 layer blocks

    // ---- CSR build: bucketed counting sort (no random sub-line stores) ----
    init_bcur<<<(nbuk + 255) / 256, 256, 0, stream>>>(bcur, nbuk);
    partition_kernel<<<PART_BLOCKS, PART_THREADS, 0, stream>>>(row, col, ew, bcur, pk, E, nbuk);
    sort_kernel<<<nbuk, 256, 0, stream>>>(pk, bcur, cw, rowptr2, N);

    // ---- premixed layer weights ----
    int total = L * DD * DD;
    prep_w<<<(total + 255) / 256, 256, 0, stream>>>(conv_w, Wp, total);

    // ---- h0 = relu(x @ Wlin + b) -> x0 (half); layer 0 reads x0 ----
    lin0_kernel<<<mt, 256, 0, stream>>>(x, w_lin, b_lin, x0, N);

    // ---- L fused layers. hin: x0, hB, hA, hB; final -> f32 out ----
    for (int l = 0; l < L; ++l) {
        const ushort* hin = (l == 0) ? x0 : ((l % 2 == 1) ? hB : hA);
        ushort* hout      = (l % 2 == 0) ? hB : hA;
        bool last = (l == L - 1);
        layer_kernel<<<gb, 256, 0, stream>>>(hin, x0, rowptr2, cw,
                                             Wp + (size_t)l * DD * DD,
                                             last ? nullptr : hout,
                                             last ? out : nullptr, N);
    }
}

// Round 18
// 299.742 us; speedup vs baseline: 1.0835x; 1.0835x over previous
//
#include <hip/hip_runtime.h>
#include <hip/hip_fp16.h>
#include <math.h>

// GCNII forward, fp16-compressed intermediates. ROUND-14 STATE RESTORED
// (empirical best: 300.1us). Rounds 15-17 tested W'-from-global (+27us),
// nontemporal streams (+4us), shfl-dense (+6us) - all regressed; the
// fused layer below is the measured local optimum.
//   h0 = relu(x @ Wlin + b)                       [lin0: tiled GEMM, M=128]
//   per layer l: h = relu((0.9*(A@h) + 0.1*x0) @ W'_l)   [ONE fused kernel]
//   W'_l = (1-beta_l) I + beta_l W_l (premixed).
// Fused layer, per block (32 nodes, 4 waves):
//   phase 1: 8-lane-group gather (1KB/instr, GSTRIDE-padded record slots)
//            -> z in registers -> staged to LDS zs[32][68] f32
//   phase 2: dense from LDS: thread = (node, 8-out slice), W' in LDS
// lin0: reg-prefetch dbuf, writes only x0. CSR build: bucketed counting
// sort (no random sub-line global stores).
// Constants: N=100000, E=1600000, H=128, D=64, L=4.

#define DD 64
#define HH 128
#define M_TILE 128
#define K_CHUNK 32
#define NPB 128            // nodes per bucket (bucket = node>>7)
#define SLOT 2560          // record slots per bucket (mean ~2046, +11 sigma)
#define NBUK_MAX 1024
#define PART_BLOCKS 256
#define PART_THREADS 1024
#define GSTRIDE 17         // padded record-slot stride (int2) -> distinct banks
#define WPAD 68            // padded row stride (floats) for Ws/zs

__device__ inline ushort f2h(float f) { return __half_as_ushort(__float2half(f)); }
__device__ inline float us2f(ushort u) { return __half2float(__ushort_as_half(u)); }

__global__ __launch_bounds__(256) void init_bcur(int* bcur, int nbuk) {
    int i = blockIdx.x * blockDim.x + threadIdx.x;
    if (i < nbuk) bcur[i] = i * SLOT;
}

// One-pass partition into bucket slots. Record: {row:17 | col_lo15:15},
// {col_hi2:2 | w_fp16:16<<2}.
__global__ __launch_bounds__(PART_THREADS) void partition_kernel(
    const int* __restrict__ row, const int* __restrict__ col,
    const float* __restrict__ ew, int* __restrict__ bcur,
    uint2* __restrict__ pk, int E, int nbuk) {
    __shared__ int cnt[NBUK_MAX], base[NBUK_MAX], rc[NBUK_MAX];
    int t = threadIdx.x;
    for (int i = t; i < nbuk; i += PART_THREADS) { cnt[i] = 0; rc[i] = 0; }
    __syncthreads();
    int chunk = (E + gridDim.x - 1) / gridDim.x;
    int s0 = blockIdx.x * chunk;
    int s1 = min(s0 + chunk, E);
    for (int e = s0 + t; e < s1; e += PART_THREADS)
        atomicAdd(&cnt[__builtin_nontemporal_load(&row[e]) >> 7], 1);
    __syncthreads();
    for (int i = t; i < nbuk; i += PART_THREADS)
        if (cnt[i] > 0) base[i] = atomicAdd(&bcur[i], cnt[i]);
    __syncthreads();
    for (int e = s0 + t; e < s1; e += PART_THREADS) {
        int r = __builtin_nontemporal_load(&row[e]);
        int c = __builtin_nontemporal_load(&col[e]);
        ushort wh = f2h(__builtin_nontemporal_load(&ew[e]));
        int b = r >> 7;
        int pos = base[b] + atomicAdd(&rc[b], 1);
        if (pos < (b + 1) * SLOT)   // defensive (SLOT is +11 sigma)
            pk[pos] = make_uint2((uint)r | (((uint)c & 0x7fffu) << 17),
                                 ((uint)c >> 15) | ((uint)wh << 2));
    }
}

// Per-bucket counting sort -> CSR segment at cw[b*SLOT ..] + rowptr2 pairs.
__global__ __launch_bounds__(256) void sort_kernel(
    const uint2* __restrict__ pk, const int* __restrict__ bcur,
    int2* __restrict__ cw, int2* __restrict__ rowptr2, int n) {
    __shared__ int hist[NPB], scan[NPB], rc[NPB];
    int b = blockIdx.x, lo = b << 7;
    int cnt = min(bcur[b] - b * SLOT, SLOT);
    const uint2* rec = pk + (size_t)b * SLOT;
    int t = threadIdx.x;
    if (t < NPB) { hist[t] = 0; rc[t] = 0; }
    __syncthreads();
    for (int i = t; i < cnt; i += 256)
        atomicAdd(&hist[(rec[i].x & 0x1ffffu) - lo], 1);
    __syncthreads();
    if (t < NPB) scan[t] = hist[t];
    __syncthreads();
    for (int off = 1; off < NPB; off <<= 1) {       // inclusive scan
        int v = (t < NPB && t >= off) ? scan[t - off] : 0;
        __syncthreads();
        if (t < NPB) scan[t] += v;
        __syncthreads();
    }
    if (t < NPB && lo + t < n) {
        int beg = b * SLOT + scan[t] - hist[t];     // exclusive base
        rowptr2[lo + t] = make_int2(beg, beg + hist[t]);
    }
    for (int i = t; i < cnt; i += 256) {
        uint2 r2 = rec[i];
        int nl = (int)(r2.x & 0x1ffffu) - lo;
        int c = (int)((r2.x >> 17) | ((r2.y & 3u) << 15));
        float w = us2f((ushort)((r2.y >> 2) & 0xffffu));
        int pos = (scan[nl] - hist[nl]) + atomicAdd(&rc[nl], 1);
        cw[b * SLOT + pos] = make_int2(c, __float_as_int(w));
    }
}

// W'_l = (1-beta_l) I + beta_l W_l, all L layers at once.
__global__ __launch_bounds__(256) void prep_w(const float* __restrict__ conv_w,
                                              float* __restrict__ Wp, int total) {
    int i = blockIdx.x * blockDim.x + threadIdx.x;
    if (i >= total) return;
    int l = i >> 12;
    int r = i & 4095;
    int d = r >> 6, j = r & 63;
    float beta = logf(0.5f / (float)(l + 1) + 1.0f);
    float v = beta * conv_w[i];
    if (d == j) v += 1.0f - beta;
    Wp[i] = v;
}

// h0 = relu(x @ Wlin + b) -> x0 only (layer-0 reads x0 directly).
// Register-tiled GEMM, thread = 8 nodes x 4 outs, 128-node tile.
// W from global (L1-hot); x tile in 16KB XOR-swizzled LDS; next x tile
// register-prefetched so HBM latency overlaps the 32-k compute.
__global__ __launch_bounds__(256) void lin0_kernel(
    const float* __restrict__ x, const float* __restrict__ Wlin,
    const float* __restrict__ b, ushort* __restrict__ x0, int n) {
    __shared__ float xs[K_CHUNK][M_TILE];      // 16 KB, swizzled columns
    int t = threadIdx.x;
    int tm = t >> 4, tn = t & 15;
    int m0 = blockIdx.x * M_TILE;

    float4 bb = *(const float4*)&b[tn * 4];
    float acc[8][4];
#pragma unroll
    for (int mi = 0; mi < 8; ++mi) {
        acc[mi][0] = bb.x; acc[mi][1] = bb.y; acc[mi][2] = bb.z; acc[mi][3] = bb.w;
    }

    // prefetch kk = 0
    float4 v[4];
#pragma unroll
    for (int i = 0; i < 4; ++i) {
        int s = t + i * 256;
        int node = s >> 3, cpos = (s & 7) * 4;
        int g = m0 + node;
        v[i] = (g < n) ? *(const float4*)&x[(size_t)g * HH + cpos]
                       : make_float4(0.f, 0.f, 0.f, 0.f);
    }

    for (int kk = 0; kk < HH; kk += K_CHUNK) {
        __syncthreads();                       // prev compute done
#pragma unroll
        for (int i = 0; i < 4; ++i) {
            int s = t + i * 256;
            int node = s >> 3, cpos = (s & 7) * 4;
            int q = (s & 7) & 3;
            int pc = node ^ (q << 3);          // swizzled column
            xs[cpos + 0][pc] = v[i].x;
            xs[cpos + 1][pc] = v[i].y;
            xs[cpos + 2][pc] = v[i].z;
            xs[cpos + 3][pc] = v[i].w;
        }
        __syncthreads();
        if (kk + K_CHUNK < HH) {               // prefetch next tile
#pragma unroll
            for (int i = 0; i < 4; ++i) {
                int s = t + i * 256;
                int node = s >> 3, cpos = (s & 7) * 4;
                int g = m0 + node;
                v[i] = (g < n)
                    ? *(const float4*)&x[(size_t)g * HH + kk + K_CHUNK + cpos]
                    : make_float4(0.f, 0.f, 0.f, 0.f);
            }
        }
#pragma unroll
        for (int k = 0; k < K_CHUNK; ++k) {
            float4 wv = *(const float4*)&Wlin[(size_t)(kk + k) * DD + tn * 4];
            int base = (tm * 8) ^ ((((k) >> 2) & 3) << 3);
            float4 xa = *(const float4*)&xs[k][base];
            float4 xb = *(const float4*)&xs[k][base + 4];
            float xm[8] = {xa.x, xa.y, xa.z, xa.w, xb.x, xb.y, xb.z, xb.w};
            float wj[4] = {wv.x, wv.y, wv.z, wv.w};
#pragma unroll
            for (int mi = 0; mi < 8; ++mi)
#pragma unroll
                for (int j = 0; j < 4; ++j)
                    acc[mi][j] += xm[mi] * wj[j];
        }
    }
#pragma unroll
    for (int mi = 0; mi < 8; ++mi) {
        int node = m0 + tm * 8 + mi;
        if (node >= n) continue;
        ushort4 o;
        o.x = f2h(fmaxf(acc[mi][0], 0.f));
        o.y = f2h(fmaxf(acc[mi][1], 0.f));
        o.z = f2h(fmaxf(acc[mi][2], 0.f));
        o.w = f2h(fmaxf(acc[mi][3], 0.f));
        *(ushort4*)&x0[(size_t)node * DD + tn * 4] = o;
    }
}

// Fused GCNII layer: z = 0.9*(A@h) + 0.1*x0 (gather, registers) ->
// LDS zs -> h = relu(z @ W') (dense from LDS). Block = 32 nodes, 4 waves.
__global__ __launch_bounds__(256) void layer_kernel(
    const ushort* __restrict__ h_in, const ushort* __restrict__ x0,
    const int2* __restrict__ rowptr2, const int2* __restrict__ cw,
    const float* __restrict__ Wp, ushort* __restrict__ h_half,
    float* __restrict__ h_f32, int n) {
    __shared__ float Ws[DD][WPAD];        // 17.4 KB premixed W'
    __shared__ float zs[32][WPAD];        // 8.7 KB z staging
    __shared__ int2 es[4][8 * GSTRIDE];   // 4.3 KB edge records
    int t = threadIdx.x;

    // cooperative W' load: 4096 floats, 16 per thread
    {
        int k = t >> 2, j0 = (t & 3) * 16;
#pragma unroll
        for (int p = 0; p < 4; ++p)
            *(float4*)&Ws[k][j0 + p * 4] =
                *(const float4*)&Wp[(size_t)k * DD + j0 + p * 4];
    }

    // ---- phase 1: gather (8-lane group per node, 8 nodes/wave) ----
    int wave = t >> 6, lane = t & 63;
    int grp = lane >> 3, sub = lane & 7;
    int2* slot = &es[wave][grp * GSTRIDE];
    int ln = wave * 8 + grp;                   // block-local node 0..31
    int node = blockIdx.x * 32 + ln;
    bool nvalid = node < n;
    int nn = nvalid ? node : (n - 1);
    int2 rp = rowptr2[nn];
    int beg = rp.x;
    int end = nvalid ? rp.y : beg;
    uint4 x0v = *(const uint4*)&x0[(size_t)nn * DD + sub * 8];

    float acc[4][8];
#pragma unroll
    for (int c = 0; c < 4; ++c)
#pragma unroll
        for (int f = 0; f < 8; ++f) acc[c][f] = 0.f;

    for (int base = beg; base < end; base += 16) {
        int m = end - base;
        if (m > 16) m = 16;
        if (sub < m) slot[sub] = cw[base + sub];
        if (sub + 8 < m) slot[sub + 8] = cw[base + sub + 8];
        // same-wave LDS write->read; compiler orders via lgkmcnt
#pragma unroll
        for (int j = 0; j < 4; ++j) {
#pragma unroll
            for (int c = 0; c < 4; ++c) {
                int idx = j * 4 + c;
                bool vld = idx < m;
                int2 r = slot[vld ? idx : 0];
                float w = vld ? __int_as_float(r.y) : 0.f;
                uint4 hv = *(const uint4*)&h_in[(size_t)r.x * DD + sub * 8];
                acc[c][0] += w * us2f((ushort)(hv.x & 0xffff));
                acc[c][1] += w * us2f((ushort)(hv.x >> 16));
                acc[c][2] += w * us2f((ushort)(hv.y & 0xffff));
                acc[c][3] += w * us2f((ushort)(hv.y >> 16));
                acc[c][4] += w * us2f((ushort)(hv.z & 0xffff));
                acc[c][5] += w * us2f((ushort)(hv.z >> 16));
                acc[c][6] += w * us2f((ushort)(hv.w & 0xffff));
                acc[c][7] += w * us2f((ushort)(hv.w >> 16));
            }
        }
    }
    {
        uint xp[4] = {x0v.x, x0v.y, x0v.z, x0v.w};
        float4 za, zb2;
        float* zo[2] = {&za.x, &zb2.x};
#pragma unroll
        for (int k = 0; k < 8; ++k) {
            float f = (acc[0][k] + acc[1][k]) + (acc[2][k] + acc[3][k]);
            float xv = (k & 1) ? us2f((ushort)(xp[k >> 1] >> 16))
                               : us2f((ushort)(xp[k >> 1] & 0xffff));
            zo[k >> 2][k & 3] = 0.9f * f + 0.1f * xv;
        }
        *(float4*)&zs[ln][sub * 8] = za;
        *(float4*)&zs[ln][sub * 8 + 4] = zb2;
    }
    __syncthreads();

    // ---- phase 2: dense h = relu(z @ W') ----
    int ln2 = t >> 3, tn = t & 7;
    int gnode = blockIdx.x * 32 + ln2;
    float o[8];
#pragma unroll
    for (int j = 0; j < 8; ++j) o[j] = 0.f;
#pragma unroll
    for (int k = 0; k < DD; ++k) {
        float zk = zs[ln2][k];                 // broadcast within 8 threads
        float4 wa = *(const float4*)&Ws[k][tn * 8];
        float4 wb = *(const float4*)&Ws[k][tn * 8 + 4];
        o[0] += zk * wa.x; o[1] += zk * wa.y;
        o[2] += zk * wa.z; o[3] += zk * wa.w;
        o[4] += zk * wb.x; o[5] += zk * wb.y;
        o[6] += zk * wb.z; o[7] += zk * wb.w;
    }
    if (gnode < n) {
#pragma unroll
        for (int j = 0; j < 8; ++j) o[j] = fmaxf(o[j], 0.f);
        if (h_f32) {
            *(float4*)&h_f32[(size_t)gnode * DD + tn * 8] =
                make_float4(o[0], o[1], o[2], o[3]);
            *(float4*)&h_f32[(size_t)gnode * DD + tn * 8 + 4] =
                make_float4(o[4], o[5], o[6], o[7]);
        } else {
            uint4 ov;
            ov.x = (uint)f2h(o[0]) | ((uint)f2h(o[1]) << 16);
            ov.y = (uint)f2h(o[2]) | ((uint)f2h(o[3]) << 16);
            ov.z = (uint)f2h(o[4]) | ((uint)f2h(o[5]) << 16);
            ov.w = (uint)f2h(o[6]) | ((uint)f2h(o[7]) << 16);
            *(uint4*)&h_half[(size_t)gnode * DD + tn * 8] = ov;
        }
    }
}

static inline size_t align256(size_t x) { return (x + 255) & ~(size_t)255; }

extern "C" void kernel_launch(void* const* d_in, const int* in_sizes, int n_in,
                              void* d_out, int out_size, void* d_ws, size_t ws_size,
                              hipStream_t stream) {
    const float* x      = (const float*)d_in[0];
    const int*   row    = (const int*)d_in[1];
    const int*   col    = (const int*)d_in[2];
    const float* ew     = (const float*)d_in[3];
    const float* w_lin  = (const float*)d_in[4];
    const float* b_lin  = (const float*)d_in[5];
    const float* conv_w = (const float*)d_in[6];
    float* out = (float*)d_out;

    const int N = in_sizes[0] / HH;          // 100000
    const int E = in_sizes[1];               // 1600000
    const int L = in_sizes[6] / (DD * DD);   // 4
    const int nbuk = (N + NPB - 1) / NPB;    // 782

    char* ws = (char*)d_ws;
    size_t off = 0;
    int* bcur = (int*)(ws + off);        off = align256(off + (size_t)NBUK_MAX * 4);
    uint2* pk = (uint2*)(ws + off);      off = align256(off + (size_t)nbuk * SLOT * 8);
    int2* cw = (int2*)(ws + off);        off = align256(off + (size_t)nbuk * SLOT * 8);
    int2* rowptr2 = (int2*)(ws + off);   off = align256(off + (size_t)N * 8);
    ushort* x0 = (ushort*)(ws + off);    off = align256(off + (size_t)N * DD * 2);
    ushort* hA = (ushort*)(ws + off);    off = align256(off + (size_t)N * DD * 2);
    ushort* hB = (ushort*)(ws + off);    off = align256(off + (size_t)N * DD * 2);
    float* Wp = (float*)(ws + off);      off = align256(off + (size_t)L * DD * DD * 4);
    (void)ws_size;

    const int mt = (N + M_TILE - 1) / M_TILE;   // 782
    const int gb = (N + 31) / 32;               // 3125 layer blocks

    // ---- CSR build: bucketed counting sort (no random sub-line stores) ----
    init_bcur<<<(nbuk + 255) / 256, 256, 0, stream>>>(bcur, nbuk);
    partition_kernel<<<PART_BLOCKS, PART_THREADS, 0, stream>>>(row, col, ew, bcur, pk, E, nbuk);
    sort_kernel<<<nbuk, 256, 0, stream>>>(pk, bcur, cw, rowptr2, N);

    // ---- premixed layer weights ----
    int total = L * DD * DD;
    prep_w<<<(total + 255) / 256, 256, 0, stream>>>(conv_w, Wp, total);

    // ---- h0 = relu(x @ Wlin + b) -> x0 (half); layer 0 reads x0 ----
    lin0_kernel<<<mt, 256, 0, stream>>>(x, w_lin, b_lin, x0, N);

    // ---- L fused layers. hin: x0, hB, hA, hB; final -> f32 out ----
    for (int l = 0; l < L; ++l) {
        const ushort* hin = (l == 0) ? x0 : ((l % 2 == 1) ? hB : hA);
        ushort* hout      = (l % 2 == 0) ? hB : hA;
        bool last = (l == L - 1);
        layer_kernel<<<gb, 256, 0, stream>>>(hin, x0, rowptr2, cw,
                                             Wp + (size_t)l * DD * DD,
                                             last ? nullptr : hout,
                                             last ? out : nullptr, N);
    }
}